// Round 5
// baseline (355.289 us; speedup 1.0000x reference)
//
#include <hip/hip_runtime.h>
#include <stdint.h>

// LeNet5-XNOR fused pipeline, round 5.
// vs round 4:
//  - conv1_sign: block-local LDS staging of x (coalesced, 1x read) then
//    ds_read_b128 register patches; kills the 3.1x global over-read and the
//    load-latency exposure that kept conv1 at ~3x its VALU floor.
//  - conv2lin: sliding uint2 window loads (42 b64 vs 180 b32 ds_reads/unit);
//    h kept in registers through fc (hsh LDS buffer deleted).
//  - sumT: two-stage partial sums, no atomics; memset launch deleted.

#define NIMG 8192

// ---------------- workspace layout ----------------
// 0      : 20 f32     mean
// 128    : 1250 u32   wp2
// 5632   : 500 f32    alpha
// 7680   : 500*20 u64 lwp
// 87808  : 64*1024 f32 partial image sums
// 350208 : 8192*196 u32 b1p

__global__ __launch_bounds__(64) void prep_k(const float* __restrict__ lw,
                                             const float* __restrict__ w2,
                                             unsigned long long* __restrict__ lwp,
                                             float* __restrict__ alpha,
                                             uint32_t* __restrict__ wp2) {
  int b = blockIdx.x, t = threadIdx.x;
  if (b < 500) {
    int j = b;
    float pa = 0.f;
    for (int k = t; k < 1250; k += 64) pa += fabsf(lw[j * 1250 + k]);
    for (int o = 32; o > 0; o >>= 1) pa += __shfl_down(pa, o, 64);
    if (t == 0) alpha[j] = pa / 1250.0f;
    if (t < 20) {
      unsigned long long m = 0;
      int base = j * 1250 + t * 64;
      int lim = 1250 - t * 64; if (lim > 64) lim = 64;
      for (int bb = 0; bb < lim; ++bb)
        if (lw[base + bb] > 0.f) m |= (1ull << bb);
      lwp[j * 20 + t] = m;
    }
  } else {
    int idx = (b - 500) * 64 + t;
    if (idx < 1250) {
      int oc = idx / 25, k = idx % 25;
      uint32_t m = 0;
      for (int ic = 0; ic < 20; ++ic)
        if (w2[(oc * 20 + ic) * 25 + k] > 0.f) m |= (1u << ic);
      wp2[idx] = m;
    }
  }
}

// Stage 1: 64 blocks x 128 images each, no atomics.
__global__ __launch_bounds__(256) void sumT_k(const float* __restrict__ x,
                                              float* __restrict__ partial) {
  int b = blockIdx.x, t = threadIdx.x;
  const float4* xv = (const float4*)x + (size_t)b * 128 * 256;
  float ax = 0.f, ay = 0.f, az = 0.f, aw = 0.f;
  for (int nn = 0; nn < 128; ++nn) {
    float4 v = xv[nn * 256 + t];
    ax += v.x; ay += v.y; az += v.z; aw += v.w;
  }
  float4 r; r.x = ax; r.y = ay; r.z = az; r.w = aw;
  ((float4*)(partial + (size_t)b * 1024))[t] = r;
}

// Stage 2: reduce partials -> T (LDS), window sums -> U, project -> mean.
__global__ __launch_bounds__(256) void mean_k(const float* __restrict__ partial,
                                              const float* __restrict__ w1,
                                              float* __restrict__ mean) {
  __shared__ float Tsh[1024];
  __shared__ double U8[25][8];
  __shared__ double U[25];
  int t = threadIdx.x;
  for (int e = t; e < 1024; e += 256) {
    double s = 0.0;
    for (int b = 0; b < 64; ++b) s += (double)partial[b * 1024 + e];
    Tsh[e] = (float)s;
  }
  __syncthreads();
  if (t < 200) {
    int tap = t >> 3, part = t & 7;
    int ky = tap / 5, kx = tap % 5;
    double s = 0.0;
    for (int p = part * 98; p < part * 98 + 98; ++p) {
      int py = p / 28, px = p % 28;
      s += (double)Tsh[(py + ky) * 32 + px + kx];
    }
    U8[tap][part] = s;
  }
  __syncthreads();
  if (t < 25) {
    double s = 0.0;
    for (int i = 0; i < 8; ++i) s += U8[t][i];
    U[t] = s;
  }
  __syncthreads();
  if (t < 20) {
    double s = 0.0;
    for (int q = 0; q < 25; ++q) s += (double)w1[t * 25 + q] * U[q];
    mean[t] = (float)(s / (8192.0 * 784.0));
  }
}

// thread = (n, 2x2 pooled block). Images staged in LDS (coalesced), patch via
// ds_read_b128. Grid 1568 blocks exactly; each block spans <= 7 images.
__global__ __launch_bounds__(256) void conv1_sign_k(const float* __restrict__ x,
                                                    const float* __restrict__ w1,
                                                    const float* __restrict__ mean,
                                                    uint32_t* __restrict__ b1p) {
  __shared__ float xs[7][1024];
  int tid = threadIdx.x;
  int B0 = blockIdx.x * 256;
  int nf = B0 / 49;
  int nl = (B0 + 255) / 49;
  int span = nl - nf + 1;  // <= 7
  for (int i = tid; i < span * 256; i += 256) {
    int im = i >> 8, el = i & 255;
    ((float4*)xs[im])[el] = ((const float4*)(x + (size_t)(nf + im) * 1024))[el];
  }
  __syncthreads();

  int gid = B0 + tid;
  int n = gid / 49;
  int u = gid - n * 49;
  int q = u / 7, pxp = u - q * 7;
  const float* base = xs[n - nf] + q * 128 + pxp * 4;
  float p[8][8];
#pragma unroll
  for (int r = 0; r < 8; ++r) {
    float4 a = *(const float4*)(base + r * 32);
    float4 b = *(const float4*)(base + r * 32 + 4);
    p[r][0] = a.x; p[r][1] = a.y; p[r][2] = a.z; p[r][3] = a.w;
    p[r][4] = b.x; p[r][5] = b.y; p[r][6] = b.z; p[r][7] = b.w;
  }
  uint32_t m00 = 0, m01 = 0, m10 = 0, m11 = 0;
#pragma unroll 2
  for (int c = 0; c < 20; ++c) {
    float s[4][4];
#pragma unroll
    for (int i = 0; i < 4; ++i)
#pragma unroll
      for (int j = 0; j < 4; ++j) s[i][j] = 0.f;
#pragma unroll
    for (int ky = 0; ky < 5; ++ky)
#pragma unroll
      for (int kx = 0; kx < 5; ++kx) {
        float wv = w1[c * 25 + ky * 5 + kx];
#pragma unroll
        for (int dy = 0; dy < 4; ++dy)
#pragma unroll
          for (int dx = 0; dx < 4; ++dx)
            s[dy][dx] += p[ky + dy][kx + dx] * wv;
      }
    float m = mean[c];
    if (s[0][0] > m || s[0][1] > m || s[1][0] > m || s[1][1] > m) m00 |= (1u << c);
    if (s[0][2] > m || s[0][3] > m || s[1][2] > m || s[1][3] > m) m01 |= (1u << c);
    if (s[2][0] > m || s[2][1] > m || s[3][0] > m || s[3][1] > m) m10 |= (1u << c);
    if (s[2][2] > m || s[2][3] > m || s[3][2] > m || s[3][3] > m) m11 |= (1u << c);
  }
  uint32_t* dst = b1p + (size_t)n * 196 + 2 * q * 14 + 2 * pxp;
  uint2 r0; r0.x = m00; r0.y = m01;
  uint2 r1; r1.x = m10; r1.y = m11;
  *(uint2*)dst = r0;
  *(uint2*)(dst + 14) = r1;
}

// Fused conv2+pool/sign+linear+fc. Block = 4 images, one wave per image.
__global__ __launch_bounds__(256) void conv2lin_k(const uint32_t* __restrict__ b1p,
                                                  const uint32_t* __restrict__ wp2,
                                                  const unsigned long long* __restrict__ lwp,
                                                  const float* __restrict__ alpha,
                                                  const float* __restrict__ fcw,
                                                  const float* __restrict__ fcb,
                                                  float* __restrict__ out) {
  __shared__ uint32_t wsh[1250];
  __shared__ uint32_t bm[4][196];
  __shared__ int sumpc[4][100];
  __shared__ signed char s2sh[4][1280];
  int tid = threadIdx.x;
  int wave = tid >> 6, lane = tid & 63;
  int n = blockIdx.x * 4 + wave;

  for (int i = tid; i < 1250; i += 256) wsh[i] = wp2[i];
#pragma unroll
  for (int rd = 0; rd < 4; ++rd) {
    int idx = rd * 64 + lane;
    if (idx < 196) bm[wave][idx] = b1p[(size_t)n * 196 + idx];
  }
  __syncthreads();

#pragma unroll
  for (int rd = 0; rd < 2; ++rd) {
    int pp = rd * 64 + lane;
    if (pp < 100) {
      int Y = pp / 10, X = pp % 10, s = 0;
#pragma unroll
      for (int ky = 0; ky < 5; ++ky)
#pragma unroll
        for (int kx = 0; kx < 5; ++kx)
          s += __popc(bm[wave][(Y + ky) * 14 + X + kx]);
      sumpc[wave][pp] = s;
    }
  }

  // conv2: unit = (oc, pooled row r); slide a 6-col window across 5 pooled cols
#pragma unroll
  for (int rd = 0; rd < 4; ++rd) {
    int unit = rd * 64 + lane;
    bool act = unit < 250;
    int cu = act ? unit : 0;
    int oc = cu / 5, r = cu % 5;
    uint32_t w[25];
#pragma unroll
    for (int i = 0; i < 25; ++i) w[i] = wsh[oc * 25 + i];
    uint32_t pa[6][6];
#pragma unroll
    for (int rr = 0; rr < 6; ++rr) {
      const uint32_t* rp = &bm[wave][(2 * r + rr) * 14];
      uint2 v0 = *(const uint2*)(rp);
      uint2 v1 = *(const uint2*)(rp + 2);
      uint2 v2 = *(const uint2*)(rp + 4);
      pa[rr][0] = v0.x; pa[rr][1] = v0.y;
      pa[rr][2] = v1.x; pa[rr][3] = v1.y;
      pa[rr][4] = v2.x; pa[rr][5] = v2.y;
    }
#pragma unroll
    for (int pc = 0; pc < 5; ++pc) {
      int best = -1000000;
#pragma unroll
      for (int dy = 0; dy < 2; ++dy)
#pragma unroll
        for (int dx = 0; dx < 2; ++dx) {
          int a = 0;
#pragma unroll
          for (int ky = 0; ky < 5; ++ky)
#pragma unroll
            for (int kx = 0; kx < 5; ++kx)
              a += __popc(w[ky * 5 + kx] & pa[dy + ky][dx + kx]);
          a = 2 * a - sumpc[wave][(2 * r + dy) * 10 + 2 * pc + dx];
          if (a > best) best = a;
        }
      if (act) s2sh[wave][5 * cu + pc] = (signed char)((best > 0) - (best < 0));
      if (pc < 4) {
#pragma unroll
        for (int rr = 0; rr < 6; ++rr) {
          pa[rr][0] = pa[rr][2]; pa[rr][1] = pa[rr][3];
          pa[rr][2] = pa[rr][4]; pa[rr][3] = pa[rr][5];
          uint2 nv = *(const uint2*)(&bm[wave][(2 * r + rr) * 14 + 2 * pc + 6]);
          pa[rr][4] = nv.x; pa[rr][5] = nv.y;
        }
      }
    }
  }
  if (lane < 30) s2sh[wave][1250 + lane] = 0;

  // ballot-pack signs; P/N masks are wave-uniform (SGPR-resident)
  unsigned long long Pm[20], Nm[20];
  int cp = 0, cn = 0;
#pragma unroll
  for (int k = 0; k < 20; ++k) {
    signed char v = s2sh[wave][k * 64 + lane];
    unsigned long long P = __ballot(v > 0);
    unsigned long long N = __ballot(v < 0);
    Pm[k] = P; Nm[k] = N;
    cp += __popcll(P); cn += __popcll(N);
  }

  // binary linear 1250->500 + clip; h stays in registers
  float hv[8];
#pragma unroll
  for (int rd = 0; rd < 8; ++rd) {
    int j = rd * 64 + lane;
    float y = 0.f;
    if (j < 500) {
      const ulonglong2* W2 = (const ulonglong2*)(lwp + (size_t)j * 20);
      int a = 0, b = 0;
#pragma unroll
      for (int i = 0; i < 10; ++i) {
        ulonglong2 w2v = W2[i];
        a += __popcll(w2v.x & Pm[2 * i]) + __popcll(w2v.y & Pm[2 * i + 1]);
        b += __popcll(w2v.x & Nm[2 * i]) + __popcll(w2v.y & Nm[2 * i + 1]);
      }
      int dot = 2 * (a - b) - cp + cn;
      y = alpha[j] * (float)dot;
      y = fminf(1.0f, fmaxf(-1.0f, y));
    }
    hv[rd] = y;
  }

  // fc 500->10, wave shuffle reduce (hv[rd]=0 for j>=500 keeps sums exact)
#pragma unroll
  for (int o = 0; o < 10; ++o) {
    float pa = 0.f;
#pragma unroll
    for (int k = 0; k < 8; ++k) {
      int j = k * 64 + lane;
      int jj = j < 500 ? j : 499;
      pa += hv[k] * fcw[o * 500 + jj];
    }
    for (int off = 32; off > 0; off >>= 1) pa += __shfl_down(pa, off, 64);
    if (lane == 0) out[(size_t)n * 10 + o] = pa + fcb[o];
  }
}

extern "C" void kernel_launch(void* const* d_in, const int* in_sizes, int n_in,
                              void* d_out, int out_size, void* d_ws, size_t ws_size,
                              hipStream_t stream) {
  const float* x   = (const float*)d_in[0];
  const float* w1  = (const float*)d_in[1];
  const float* w2  = (const float*)d_in[2];
  const float* lw  = (const float*)d_in[3];
  const float* fcw = (const float*)d_in[4];
  const float* fcb = (const float*)d_in[5];
  float* out = (float*)d_out;
  char* ws = (char*)d_ws;

  float*    mean  = (float*)(ws + 0);
  uint32_t* wp2   = (uint32_t*)(ws + 128);
  float*    alpha = (float*)(ws + 5632);
  unsigned long long* lwp = (unsigned long long*)(ws + 7680);
  float*    partial = (float*)(ws + 87808);
  uint32_t* b1p   = (uint32_t*)(ws + 350208);

  prep_k<<<520, 64, 0, stream>>>(lw, w2, lwp, alpha, wp2);
  sumT_k<<<64, 256, 0, stream>>>(x, partial);
  mean_k<<<1, 256, 0, stream>>>(partial, w1, mean);
  conv1_sign_k<<<1568, 256, 0, stream>>>(x, w1, mean, b1p);
  conv2lin_k<<<2048, 256, 0, stream>>>(b1p, wp2, lwp, alpha, fcw, fcb, out);
}

// Round 6
// 285.607 us; speedup vs baseline: 1.2440x; 1.2440x over previous
//
#include <hip/hip_runtime.h>
#include <stdint.h>

// LeNet5-XNOR fused pipeline, round 6.
// vs round 4 (round 5's sliding-window regression reverted):
//  - conv2lin: conv2 inner rewritten as row-accumulator form — each of the 6
//    input bitmask rows is loaded ONCE per unit (7 aligned uint2), and all 20
//    conv outputs of the unit accumulate from registers. Same tap count,
//    ~5x fewer LDS reads than r4's per-window streaming. Controlled VGPR
//    (~90): w[25]+row[14]+acc[20].
//  - conv1_sign: r4 structure + fmax4-then-single-compare per mask bit.
//  - sumT: 128 blocks, atomic-free partials.

#define NIMG 8192

// ---------------- workspace layout ----------------
// 0      : 20 f32     mean
// 128    : 1250 u32   wp2
// 5632   : 500 f32    alpha
// 7680   : 500*20 u64 lwp
// 87808  : 128*1024 f32 partial image sums
// 612096 : 8192*196 u32 b1p

__global__ __launch_bounds__(64) void prep_k(const float* __restrict__ lw,
                                             const float* __restrict__ w2,
                                             unsigned long long* __restrict__ lwp,
                                             float* __restrict__ alpha,
                                             uint32_t* __restrict__ wp2) {
  int b = blockIdx.x, t = threadIdx.x;
  if (b < 500) {
    int j = b;
    float pa = 0.f;
    for (int k = t; k < 1250; k += 64) pa += fabsf(lw[j * 1250 + k]);
    for (int o = 32; o > 0; o >>= 1) pa += __shfl_down(pa, o, 64);
    if (t == 0) alpha[j] = pa / 1250.0f;
    if (t < 20) {
      unsigned long long m = 0;
      int base = j * 1250 + t * 64;
      int lim = 1250 - t * 64; if (lim > 64) lim = 64;
      for (int bb = 0; bb < lim; ++bb)
        if (lw[base + bb] > 0.f) m |= (1ull << bb);
      lwp[j * 20 + t] = m;
    }
  } else {
    int idx = (b - 500) * 64 + t;
    if (idx < 1250) {
      int oc = idx / 25, k = idx % 25;
      uint32_t m = 0;
      for (int ic = 0; ic < 20; ++ic)
        if (w2[(oc * 20 + ic) * 25 + k] > 0.f) m |= (1u << ic);
      wp2[idx] = m;
    }
  }
}

// 128 blocks x 64 images, no atomics.
__global__ __launch_bounds__(256) void sumT_k(const float* __restrict__ x,
                                              float* __restrict__ partial) {
  int b = blockIdx.x, t = threadIdx.x;
  const float4* xv = (const float4*)x + (size_t)b * 64 * 256;
  float ax = 0.f, ay = 0.f, az = 0.f, aw = 0.f;
  for (int nn = 0; nn < 64; ++nn) {
    float4 v = xv[nn * 256 + t];
    ax += v.x; ay += v.y; az += v.z; aw += v.w;
  }
  float4 r; r.x = ax; r.y = ay; r.z = az; r.w = aw;
  ((float4*)(partial + (size_t)b * 1024))[t] = r;
}

__global__ __launch_bounds__(256) void mean_k(const float* __restrict__ partial,
                                              const float* __restrict__ w1,
                                              float* __restrict__ mean) {
  __shared__ float Tsh[1024];
  __shared__ double U8[25][8];
  __shared__ double U[25];
  int t = threadIdx.x;
  for (int e = t; e < 1024; e += 256) {
    double s = 0.0;
    for (int b = 0; b < 128; ++b) s += (double)partial[b * 1024 + e];
    Tsh[e] = (float)s;
  }
  __syncthreads();
  if (t < 200) {
    int tap = t >> 3, part = t & 7;
    int ky = tap / 5, kx = tap % 5;
    double s = 0.0;
    for (int p = part * 98; p < part * 98 + 98; ++p) {
      int py = p / 28, px = p % 28;
      s += (double)Tsh[(py + ky) * 32 + px + kx];
    }
    U8[tap][part] = s;
  }
  __syncthreads();
  if (t < 25) {
    double s = 0.0;
    for (int i = 0; i < 8; ++i) s += U8[t][i];
    U[t] = s;
  }
  __syncthreads();
  if (t < 20) {
    double s = 0.0;
    for (int q = 0; q < 25; ++q) s += (double)w1[t * 25 + q] * U[q];
    mean[t] = (float)(s / (8192.0 * 784.0));
  }
}

// thread = (n, 2x2 pooled block). 8x8 patch via aligned float4 from global.
// Grid 1568 blocks exactly.
__global__ __launch_bounds__(256) void conv1_sign_k(const float* __restrict__ x,
                                                    const float* __restrict__ w1,
                                                    const float* __restrict__ mean,
                                                    uint32_t* __restrict__ b1p) {
  unsigned gid = blockIdx.x * 256 + threadIdx.x;
  unsigned n = gid / 49u;
  unsigned u = gid % 49u;
  unsigned q = u / 7u, pxp = u % 7u;
  const float* base = x + (size_t)n * 1024 + q * 128 + pxp * 4;
  float p[8][8];
#pragma unroll
  for (int r = 0; r < 8; ++r) {
    float4 a = *(const float4*)(base + r * 32);
    float4 b = *(const float4*)(base + r * 32 + 4);
    p[r][0] = a.x; p[r][1] = a.y; p[r][2] = a.z; p[r][3] = a.w;
    p[r][4] = b.x; p[r][5] = b.y; p[r][6] = b.z; p[r][7] = b.w;
  }
  uint32_t m00 = 0, m01 = 0, m10 = 0, m11 = 0;
  for (int c = 0; c < 20; ++c) {
    float s[4][4];
#pragma unroll
    for (int i = 0; i < 4; ++i)
#pragma unroll
      for (int j = 0; j < 4; ++j) s[i][j] = 0.f;
#pragma unroll
    for (int ky = 0; ky < 5; ++ky)
#pragma unroll
      for (int kx = 0; kx < 5; ++kx) {
        float wv = w1[c * 25 + ky * 5 + kx];
#pragma unroll
        for (int dy = 0; dy < 4; ++dy)
#pragma unroll
          for (int dx = 0; dx < 4; ++dx)
            s[dy][dx] += p[ky + dy][kx + dx] * wv;
      }
    float m = mean[c];
    float x00 = fmaxf(fmaxf(s[0][0], s[0][1]), fmaxf(s[1][0], s[1][1]));
    float x01 = fmaxf(fmaxf(s[0][2], s[0][3]), fmaxf(s[1][2], s[1][3]));
    float x10 = fmaxf(fmaxf(s[2][0], s[2][1]), fmaxf(s[3][0], s[3][1]));
    float x11 = fmaxf(fmaxf(s[2][2], s[2][3]), fmaxf(s[3][2], s[3][3]));
    m00 |= (x00 > m) ? (1u << c) : 0u;
    m01 |= (x01 > m) ? (1u << c) : 0u;
    m10 |= (x10 > m) ? (1u << c) : 0u;
    m11 |= (x11 > m) ? (1u << c) : 0u;
  }
  uint32_t* dst = b1p + (size_t)n * 196 + 2 * q * 14 + 2 * pxp;
  uint2 r0; r0.x = m00; r0.y = m01;
  uint2 r1; r1.x = m10; r1.y = m11;
  *(uint2*)dst = r0;
  *(uint2*)(dst + 14) = r1;
}

// Fused conv2+pool/sign+linear+fc. Block = 4 images, one wave per image.
__global__ __launch_bounds__(256) void conv2lin_k(const uint32_t* __restrict__ b1p,
                                                  const uint32_t* __restrict__ wp2,
                                                  const unsigned long long* __restrict__ lwp,
                                                  const float* __restrict__ alpha,
                                                  const float* __restrict__ fcw,
                                                  const float* __restrict__ fcb,
                                                  float* __restrict__ out) {
  __shared__ uint32_t wsh[1250];
  __shared__ uint32_t bm[4][196];
  __shared__ int sumpc[4][100];
  __shared__ signed char s2sh[4][1280];
  __shared__ float hsh[4][512];
  int tid = threadIdx.x;
  int wave = tid >> 6, lane = tid & 63;
  int n = blockIdx.x * 4 + wave;

  for (int i = tid; i < 1250; i += 256) wsh[i] = wp2[i];
#pragma unroll
  for (int rd = 0; rd < 4; ++rd) {
    int idx = rd * 64 + lane;
    if (idx < 196) bm[wave][idx] = b1p[(size_t)n * 196 + idx];
  }
  __syncthreads();

#pragma unroll
  for (int rd = 0; rd < 2; ++rd) {
    int pp = rd * 64 + lane;
    if (pp < 100) {
      int Y = pp / 10, X = pp % 10, s = 0;
#pragma unroll
      for (int ky = 0; ky < 5; ++ky)
#pragma unroll
        for (int kx = 0; kx < 5; ++kx)
          s += __popc(bm[wave][(Y + ky) * 14 + X + kx]);
      sumpc[wave][pp] = s;
    }
  }

  // conv2: unit = (oc, pooled row r). Row-accumulator form: each of the 6
  // input rows is loaded once (7 aligned uint2); 20 conv outputs accumulate.
#pragma unroll
  for (int rd = 0; rd < 4; ++rd) {
    int unit = rd * 64 + lane;
    if (unit < 250) {
      int oc = unit / 5, r = unit % 5;
      uint32_t w[25];
#pragma unroll
      for (int i = 0; i < 25; ++i) w[i] = wsh[oc * 25 + i];
      int acc[2][10];
#pragma unroll
      for (int i = 0; i < 2; ++i)
#pragma unroll
        for (int j = 0; j < 10; ++j) acc[i][j] = 0;
#pragma unroll
      for (int ir = 0; ir < 6; ++ir) {
        uint32_t row[14];
        const uint32_t* rp = &bm[wave][(2 * r + ir) * 14];
#pragma unroll
        for (int h = 0; h < 7; ++h) {
          uint2 v = *(const uint2*)(rp + 2 * h);
          row[2 * h] = v.x; row[2 * h + 1] = v.y;
        }
#pragma unroll
        for (int cr = 0; cr < 2; ++cr) {
          int ky = ir - cr;
          if (ky >= 0 && ky <= 4) {
#pragma unroll
            for (int kx = 0; kx < 5; ++kx) {
              uint32_t wv = w[ky * 5 + kx];
#pragma unroll
              for (int cc = 0; cc < 10; ++cc)
                acc[cr][cc] += __popc(wv & row[cc + kx]);
            }
          }
        }
      }
#pragma unroll
      for (int pc = 0; pc < 5; ++pc) {
        int v00 = 2 * acc[0][2 * pc]     - sumpc[wave][(2 * r) * 10 + 2 * pc];
        int v01 = 2 * acc[0][2 * pc + 1] - sumpc[wave][(2 * r) * 10 + 2 * pc + 1];
        int v10 = 2 * acc[1][2 * pc]     - sumpc[wave][(2 * r + 1) * 10 + 2 * pc];
        int v11 = 2 * acc[1][2 * pc + 1] - sumpc[wave][(2 * r + 1) * 10 + 2 * pc + 1];
        int b0 = v00 > v01 ? v00 : v01;
        int b1 = v10 > v11 ? v10 : v11;
        int best = b0 > b1 ? b0 : b1;
        s2sh[wave][5 * unit + pc] = (signed char)((best > 0) - (best < 0));
      }
    }
  }
  if (lane < 30) s2sh[wave][1250 + lane] = 0;

  // ballot-pack signs; P/N masks are wave-uniform (SGPR-resident)
  unsigned long long Pm[20], Nm[20];
  int cp = 0, cn = 0;
#pragma unroll
  for (int k = 0; k < 20; ++k) {
    signed char v = s2sh[wave][k * 64 + lane];
    unsigned long long P = __ballot(v > 0);
    unsigned long long N = __ballot(v < 0);
    Pm[k] = P; Nm[k] = N;
    cp += __popcll(P); cn += __popcll(N);
  }

  // binary linear 1250->500 + clip
#pragma unroll
  for (int rd = 0; rd < 8; ++rd) {
    int j = rd * 64 + lane;
    float y = 0.f;
    if (j < 500) {
      const ulonglong2* W2 = (const ulonglong2*)(lwp + (size_t)j * 20);
      int a = 0, b = 0;
#pragma unroll
      for (int i = 0; i < 10; ++i) {
        ulonglong2 w2v = W2[i];
        a += __popcll(w2v.x & Pm[2 * i]) + __popcll(w2v.y & Pm[2 * i + 1]);
        b += __popcll(w2v.x & Nm[2 * i]) + __popcll(w2v.y & Nm[2 * i + 1]);
      }
      int dot = 2 * (a - b) - cp + cn;
      y = alpha[j] * (float)dot;
      y = fminf(1.0f, fmaxf(-1.0f, y));
    }
    hsh[wave][rd * 64 + lane] = y;
  }

  // fc 500->10, wave shuffle reduce
  float hv[8];
#pragma unroll
  for (int k = 0; k < 8; ++k) hv[k] = hsh[wave][k * 64 + lane];
#pragma unroll
  for (int o = 0; o < 10; ++o) {
    float pa = 0.f;
#pragma unroll
    for (int k = 0; k < 8; ++k) {
      int j = k * 64 + lane;
      if (j < 500) pa += hv[k] * fcw[o * 500 + j];
    }
    for (int off = 32; off > 0; off >>= 1) pa += __shfl_down(pa, off, 64);
    if (lane == 0) out[(size_t)n * 10 + o] = pa + fcb[o];
  }
}

extern "C" void kernel_launch(void* const* d_in, const int* in_sizes, int n_in,
                              void* d_out, int out_size, void* d_ws, size_t ws_size,
                              hipStream_t stream) {
  const float* x   = (const float*)d_in[0];
  const float* w1  = (const float*)d_in[1];
  const float* w2  = (const float*)d_in[2];
  const float* lw  = (const float*)d_in[3];
  const float* fcw = (const float*)d_in[4];
  const float* fcb = (const float*)d_in[5];
  float* out = (float*)d_out;
  char* ws = (char*)d_ws;

  float*    mean  = (float*)(ws + 0);
  uint32_t* wp2   = (uint32_t*)(ws + 128);
  float*    alpha = (float*)(ws + 5632);
  unsigned long long* lwp = (unsigned long long*)(ws + 7680);
  float*    partial = (float*)(ws + 87808);
  uint32_t* b1p   = (uint32_t*)(ws + 612096);

  prep_k<<<520, 64, 0, stream>>>(lw, w2, lwp, alpha, wp2);
  sumT_k<<<128, 256, 0, stream>>>(x, partial);
  mean_k<<<1, 256, 0, stream>>>(partial, w1, mean);
  conv1_sign_k<<<1568, 256, 0, stream>>>(x, w1, mean, b1p);
  conv2lin_k<<<2048, 256, 0, stream>>>(b1p, wp2, lwp, alpha, fcw, fcb, out);
}

// Round 8
// 258.890 us; speedup vs baseline: 1.3724x; 1.1032x over previous
//
#include <hip/hip_runtime.h>
#include <stdint.h>

// LeNet5-XNOR fused pipeline, round 8.
// vs round 7: conv1 MFMA switched from bf16 2-limb split (~2^-16, ~2000
// boundary flips -> absmax 0.197 FAIL) to fp16 2-limb split (~2^-23, ~12
// flips — same band as the passing fp32 kernel's summation-order noise).
// Lo limbs pre-scaled x4096 to dodge fp16 subnormals (robust to MFMA FTZ);
// recombined as acc0 + acc1/4096. Same 6-MFMA count, same verified
// fragment/epilogue algebra. conv2lin remains the round-4 version.

#define NIMG 8192

typedef __attribute__((ext_vector_type(8))) _Float16 f16x8;
typedef __attribute__((ext_vector_type(16))) float f32x16;

// ---------------- workspace layout ----------------
// 0      : 20 f32     mean
// 128    : 1250 u32   wp2
// 5632   : 500 f32    alpha
// 7680   : 500*20 u64 lwp
// 87808  : 128*1024 f32 partial image sums
// 612096 : 8192*196 u32 b1p

__global__ __launch_bounds__(64) void prep_k(const float* __restrict__ lw,
                                             const float* __restrict__ w2,
                                             unsigned long long* __restrict__ lwp,
                                             float* __restrict__ alpha,
                                             uint32_t* __restrict__ wp2) {
  int b = blockIdx.x, t = threadIdx.x;
  if (b < 500) {
    int j = b;
    float pa = 0.f;
    for (int k = t; k < 1250; k += 64) pa += fabsf(lw[j * 1250 + k]);
    for (int o = 32; o > 0; o >>= 1) pa += __shfl_down(pa, o, 64);
    if (t == 0) alpha[j] = pa / 1250.0f;
    if (t < 20) {
      unsigned long long m = 0;
      int base = j * 1250 + t * 64;
      int lim = 1250 - t * 64; if (lim > 64) lim = 64;
      for (int bb = 0; bb < lim; ++bb)
        if (lw[base + bb] > 0.f) m |= (1ull << bb);
      lwp[j * 20 + t] = m;
    }
  } else {
    int idx = (b - 500) * 64 + t;
    if (idx < 1250) {
      int oc = idx / 25, k = idx % 25;
      uint32_t m = 0;
      for (int ic = 0; ic < 20; ++ic)
        if (w2[(oc * 20 + ic) * 25 + k] > 0.f) m |= (1u << ic);
      wp2[idx] = m;
    }
  }
}

__global__ __launch_bounds__(256) void sumT_k(const float* __restrict__ x,
                                              float* __restrict__ partial) {
  int b = blockIdx.x, t = threadIdx.x;
  const float4* xv = (const float4*)x + (size_t)b * 64 * 256;
  float ax = 0.f, ay = 0.f, az = 0.f, aw = 0.f;
  for (int nn = 0; nn < 64; ++nn) {
    float4 v = xv[nn * 256 + t];
    ax += v.x; ay += v.y; az += v.z; aw += v.w;
  }
  float4 r; r.x = ax; r.y = ay; r.z = az; r.w = aw;
  ((float4*)(partial + (size_t)b * 1024))[t] = r;
}

__global__ __launch_bounds__(256) void mean_k(const float* __restrict__ partial,
                                              const float* __restrict__ w1,
                                              float* __restrict__ mean) {
  __shared__ float Tsh[1024];
  __shared__ double U8[25][8];
  __shared__ double U[25];
  int t = threadIdx.x;
  for (int e = t; e < 1024; e += 256) {
    double s = 0.0;
    for (int b = 0; b < 128; ++b) s += (double)partial[b * 1024 + e];
    Tsh[e] = (float)s;
  }
  __syncthreads();
  if (t < 200) {
    int tap = t >> 3, part = t & 7;
    int ky = tap / 5, kx = tap % 5;
    double s = 0.0;
    for (int p = part * 98; p < part * 98 + 98; ++p) {
      int py = p / 28, px = p % 28;
      s += (double)Tsh[(py + ky) * 32 + px + kx];
    }
    U8[tap][part] = s;
  }
  __syncthreads();
  if (t < 25) {
    double s = 0.0;
    for (int i = 0; i < 8; ++i) s += U8[t][i];
    U[t] = s;
  }
  __syncthreads();
  if (t < 20) {
    double s = 0.0;
    for (int q = 0; q < 25; ++q) s += (double)w1[t * 25 + q] * U[q];
    mean[t] = (float)(s / (8192.0 * 784.0));
  }
}

__device__ inline uint32_t pack_f16_pair(float fv) {
  _Float16 h = (_Float16)fv;
  float rem = fv - (float)h;
  _Float16 l = (_Float16)(rem * 4096.0f);
  uint32_t hb = (uint32_t)__builtin_bit_cast(unsigned short, h);
  uint32_t lb = (uint32_t)__builtin_bit_cast(unsigned short, l);
  return (hb << 16) | lb;
}

// conv1 via MFMA (fp16 2-limb split). One wave per image; block = 4 images.
__global__ __launch_bounds__(256) void conv1_mfma_k(const float* __restrict__ x,
                                                    const float* __restrict__ w1,
                                                    const float* __restrict__ mean,
                                                    uint32_t* __restrict__ b1p) {
  __shared__ uint32_t ximg[4][1032];  // (f16_hi<<16)|f16_lo(x4096)
  int tid = threadIdx.x;
  int wave = tid >> 6, lane = tid & 63;
  int n = blockIdx.x * 4 + wave;
  uint32_t* xs = ximg[wave];

  // ---- stage image as fp16 limb pairs ----
  const float4* xin = (const float4*)(x + (size_t)n * 1024);
#pragma unroll
  for (int i = 0; i < 4; ++i) {
    float4 v = xin[i * 64 + lane];
    float fv[4] = {v.x, v.y, v.z, v.w};
#pragma unroll
    for (int e = 0; e < 4; ++e)
      xs[4 * (i * 64 + lane) + e] = pack_f16_pair(fv[e]);
  }

  // ---- B fragments (weights hi/lo, 2 K-halves) ----
  int bc = lane & 31;          // channel (N dim)
  int khsel = lane >> 5;       // 8-k group
  f16x8 Bh[2], Bl[2];
#pragma unroll
  for (int kh = 0; kh < 2; ++kh)
#pragma unroll
    for (int j = 0; j < 8; ++j) {
      int t = kh * 16 + khsel * 8 + j;
      float wv = (bc < 20 && t < 25) ? w1[bc * 25 + t] : 0.f;
      uint32_t pp = pack_f16_pair(wv);
      Bh[kh][j] = __builtin_bit_cast(_Float16, (unsigned short)(pp >> 16));
      Bl[kh][j] = __builtin_bit_cast(_Float16, (unsigned short)(pp & 0xffffu));
    }
  float mv = (bc < 20) ? mean[bc] : 3.0e38f;

  // ---- per-lane A-read offsets ----
  int offs[2][8];
#pragma unroll
  for (int kh = 0; kh < 2; ++kh)
#pragma unroll
    for (int j = 0; j < 8; ++j) {
      int t = kh * 16 + khsel * 8 + j;
      if (t > 24) t = 24;  // pad taps multiply zero weights
      offs[kh][j] = (t / 5) * 32 + (t % 5);
    }

  int m = lane & 31;  // output px (M dim); 28..31 garbage
  const float INV = 1.0f / 4096.0f;

  for (int pp = 0; pp < 14; ++pp) {
    unsigned long long bacc[16];
#pragma unroll
    for (int r = 0; r < 16; ++r) bacc[r] = 0ull;
#pragma unroll
    for (int py2 = 0; py2 < 2; ++py2) {
      int py = 2 * pp + py2;
      int base = py * 32 + m;
      f16x8 Ah[2], Al[2];
#pragma unroll
      for (int kh = 0; kh < 2; ++kh)
#pragma unroll
        for (int j = 0; j < 8; ++j) {
          uint32_t v = xs[base + offs[kh][j]];
          Ah[kh][j] = __builtin_bit_cast(_Float16, (unsigned short)(v >> 16));
          Al[kh][j] = __builtin_bit_cast(_Float16, (unsigned short)(v & 0xffffu));
        }
      f32x16 acc0, acc1;
#pragma unroll
      for (int i = 0; i < 16; ++i) { acc0[i] = 0.f; acc1[i] = 0.f; }
      acc0 = __builtin_amdgcn_mfma_f32_32x32x16_f16(Ah[0], Bh[0], acc0, 0, 0, 0);
      acc0 = __builtin_amdgcn_mfma_f32_32x32x16_f16(Ah[1], Bh[1], acc0, 0, 0, 0);
      acc1 = __builtin_amdgcn_mfma_f32_32x32x16_f16(Ah[0], Bl[0], acc1, 0, 0, 0);
      acc1 = __builtin_amdgcn_mfma_f32_32x32x16_f16(Ah[1], Bl[1], acc1, 0, 0, 0);
      acc1 = __builtin_amdgcn_mfma_f32_32x32x16_f16(Al[0], Bh[0], acc1, 0, 0, 0);
      acc1 = __builtin_amdgcn_mfma_f32_32x32x16_f16(Al[1], Bh[1], acc1, 0, 0, 0);
      // C/D: channel = lane&31, px = (r&3) + 8*(r>>2) + 4*(lane>>5)
#pragma unroll
      for (int r = 0; r < 16; ++r)
        bacc[r] |= __ballot((acc0[r] + INV * acc1[r]) > mv);
    }
    uint32_t pm = 0;
#pragma unroll
    for (int pc = 0; pc < 14; ++pc) {
      int px0 = 2 * pc;
      int r0 = (px0 & 3) + 4 * (px0 >> 3);
      int h0 = (px0 >> 2) & 1;
      unsigned long long mm = bacc[r0] | bacc[r0 + 1];
      uint32_t val = (uint32_t)(mm >> (32 * h0));
      if (lane == pc) pm = val;
    }
    if (lane < 14) b1p[(size_t)n * 196 + pp * 14 + lane] = pm;
  }
}

// Fused conv2+pool/sign+linear+fc. Round-4 version verbatim.
__global__ __launch_bounds__(256) void conv2lin_k(const uint32_t* __restrict__ b1p,
                                                  const uint32_t* __restrict__ wp2,
                                                  const unsigned long long* __restrict__ lwp,
                                                  const float* __restrict__ alpha,
                                                  const float* __restrict__ fcw,
                                                  const float* __restrict__ fcb,
                                                  float* __restrict__ out) {
  __shared__ uint32_t wsh[1250];
  __shared__ uint32_t bm[4][196];
  __shared__ int sumpc[4][100];
  __shared__ signed char s2sh[4][1280];
  __shared__ float hsh[4][512];
  int tid = threadIdx.x;
  int wave = tid >> 6, lane = tid & 63;
  int n = blockIdx.x * 4 + wave;

  for (int i = tid; i < 1250; i += 256) wsh[i] = wp2[i];
#pragma unroll
  for (int rd = 0; rd < 4; ++rd) {
    int idx = rd * 64 + lane;
    if (idx < 196) bm[wave][idx] = b1p[(size_t)n * 196 + idx];
  }
  __syncthreads();

#pragma unroll
  for (int rd = 0; rd < 2; ++rd) {
    int pp = rd * 64 + lane;
    if (pp < 100) {
      int Y = pp / 10, X = pp % 10, s = 0;
#pragma unroll
      for (int ky = 0; ky < 5; ++ky)
#pragma unroll
        for (int kx = 0; kx < 5; ++kx)
          s += __popc(bm[wave][(Y + ky) * 14 + X + kx]);
      sumpc[wave][pp] = s;
    }
  }

#pragma unroll
  for (int rd = 0; rd < 4; ++rd) {
    int unit = rd * 64 + lane;
    if (unit < 250) {
      int oc = unit / 5, r = unit % 5;
      uint32_t w[25];
#pragma unroll
      for (int i = 0; i < 25; ++i) w[i] = wsh[oc * 25 + i];
      for (int pc = 0; pc < 5; ++pc) {
        uint32_t pa[6][6];
#pragma unroll
        for (int rr = 0; rr < 6; ++rr)
#pragma unroll
          for (int cc = 0; cc < 6; ++cc)
            pa[rr][cc] = bm[wave][(2 * r + rr) * 14 + 2 * pc + cc];
        int best = -1000000;
#pragma unroll
        for (int dy = 0; dy < 2; ++dy)
#pragma unroll
          for (int dx = 0; dx < 2; ++dx) {
            int a = 0;
#pragma unroll
            for (int ky = 0; ky < 5; ++ky)
#pragma unroll
              for (int kx = 0; kx < 5; ++kx)
                a += __popc(w[ky * 5 + kx] & pa[dy + ky][dx + kx]);
            a = 2 * a - sumpc[wave][(2 * r + dy) * 10 + 2 * pc + dx];
            if (a > best) best = a;
          }
        s2sh[wave][5 * unit + pc] = (signed char)((best > 0) - (best < 0));
      }
    }
  }
  if (lane < 30) s2sh[wave][1250 + lane] = 0;

  unsigned long long Pm[20], Nm[20];
  int cp = 0, cn = 0;
#pragma unroll
  for (int k = 0; k < 20; ++k) {
    signed char v = s2sh[wave][k * 64 + lane];
    unsigned long long P = __ballot(v > 0);
    unsigned long long N = __ballot(v < 0);
    Pm[k] = P; Nm[k] = N;
    cp += __popcll(P); cn += __popcll(N);
  }

#pragma unroll
  for (int rd = 0; rd < 8; ++rd) {
    int j = rd * 64 + lane;
    float y = 0.f;
    if (j < 500) {
      const ulonglong2* W2 = (const ulonglong2*)(lwp + (size_t)j * 20);
      int a = 0, b = 0;
#pragma unroll
      for (int i = 0; i < 10; ++i) {
        ulonglong2 w2v = W2[i];
        a += __popcll(w2v.x & Pm[2 * i]) + __popcll(w2v.y & Pm[2 * i + 1]);
        b += __popcll(w2v.x & Nm[2 * i]) + __popcll(w2v.y & Nm[2 * i + 1]);
      }
      int dot = 2 * (a - b) - cp + cn;
      y = alpha[j] * (float)dot;
      y = fminf(1.0f, fmaxf(-1.0f, y));
    }
    hsh[wave][rd * 64 + lane] = y;
  }

  float hv[8];
#pragma unroll
  for (int k = 0; k < 8; ++k) hv[k] = hsh[wave][k * 64 + lane];
#pragma unroll
  for (int o = 0; o < 10; ++o) {
    float pa = 0.f;
#pragma unroll
    for (int k = 0; k < 8; ++k) {
      int j = k * 64 + lane;
      if (j < 500) pa += hv[k] * fcw[o * 500 + j];
    }
    for (int off = 32; off > 0; off >>= 1) pa += __shfl_down(pa, off, 64);
    if (lane == 0) out[(size_t)n * 10 + o] = pa + fcb[o];
  }
}

extern "C" void kernel_launch(void* const* d_in, const int* in_sizes, int n_in,
                              void* d_out, int out_size, void* d_ws, size_t ws_size,
                              hipStream_t stream) {
  const float* x   = (const float*)d_in[0];
  const float* w1  = (const float*)d_in[1];
  const float* w2  = (const float*)d_in[2];
  const float* lw  = (const float*)d_in[3];
  const float* fcw = (const float*)d_in[4];
  const float* fcb = (const float*)d_in[5];
  float* out = (float*)d_out;
  char* ws = (char*)d_ws;

  float*    mean  = (float*)(ws + 0);
  uint32_t* wp2   = (uint32_t*)(ws + 128);
  float*    alpha = (float*)(ws + 5632);
  unsigned long long* lwp = (unsigned long long*)(ws + 7680);
  float*    partial = (float*)(ws + 87808);
  uint32_t* b1p   = (uint32_t*)(ws + 612096);

  prep_k<<<520, 64, 0, stream>>>(lw, w2, lwp, alpha, wp2);
  sumT_k<<<128, 256, 0, stream>>>(x, partial);
  mean_k<<<1, 256, 0, stream>>>(partial, w1, mean);
  conv1_mfma_k<<<2048, 256, 0, stream>>>(x, w1, mean, b1p);
  conv2lin_k<<<2048, 256, 0, stream>>>(b1p, wp2, lwp, alpha, fcw, fcb, out);
}